// Round 6
// baseline (662.181 us; speedup 1.0000x reference)
//
#include <hip/hip_runtime.h>

// Problem constants
#define NN 128
#define CC 64          // C_IN == C_OUT
#define TT 256
#define VV 25
#define NSUB 3
#define TCH 8                  // t-rows per block tile
#define LPOS (TCH*VV)          // 200 positions per block tile
#define NCHUNK (TT/TCH)        // 32 chunks per n
#define CNT (NN*TT*VV)         // 819200 positions per channel
#define XSTR 204               // padded LDS row stride (%4==0 so float4 staging stays aligned)
#define WROW (VV*CC)           // 1600: c-row stride of transposed W [c][v][o]

// workspace layout (float offsets)
#define WS_ALPHA 80     // 64:  BN scale alpha[o]
#define WS_GSUM 144     // 64:  global sum of y = Wx (bias cancels under BN)
#define WS_GSQ  208     // 64:  global sum of y^2
#define WS_W    320     // 25*64*64: W_eff stored TRANSPOSED [c][v][o]
#define WS_BFIN (WS_W + VV*CC*CC)   // 64: bfin[o] = beta - alpha*meanY

// fused: rowsums (in LDS), W_eff build (transposed), and gsum/gsq zeroing.
// NOTE: g_b bias is NOT needed anywhere — training-mode BN subtracts the
// channel mean, so a per-channel constant added to hidden cancels exactly.
__global__ void k_weff(const float* __restrict__ A, const float* __restrict__ ga,
                       const float* __restrict__ gw, float* __restrict__ ws) {
    __shared__ float S[NSUB*VV];
    int tid = threadIdx.x;
    if (tid < NSUB*VV) {
        int i = tid / VV, v = tid % VV;
        const float* pa = A  + (i*VV + v)*VV;
        const float* pg = ga + (i*VV + v)*VV;
        float s = 0.f;
        for (int w2 = 0; w2 < VV; ++w2) s += pa[w2] + pg[w2];
        S[tid] = s;
    }
    __syncthreads();
    int idx = blockIdx.x*256 + tid;
    int v = idx >> 12;
    int c = (idx >> 6) & 63;
    int o = idx & 63;
    float acc = 0.f;
    #pragma unroll
    for (int i = 0; i < NSUB; ++i)
        acc = fmaf(gw[(i*CC + o)*CC + c], 1.f + S[i*VV + v], acc);
    ws[WS_W + c*WROW + v*CC + o] = acc;          // transposed store [c][v][o]
    if (blockIdx.x == 1 && tid < 128)
        ws[WS_GSUM + tid] = 0.f;   // zeros gsum(64)+gsq(64), contiguous
}

// Single heavy GEMM pass: y[n,o,t,v] = sum_c W[c][v][o] * x[n,c,t,v].
//   - stores y to d_out (scratch until k_fin finalizes in-place)
//   - accumulates per-channel sum(y), sum(y^2) for BN stats
// Structure proven in r5 (84 VGPR, no spill):
//   block = (n, 8-t chunk); Xs[c][t*25+v] staged coalesced, row stride 204.
//   thread (tid<200): og = tid&7 (o-octet), v = tid>>3; xv[8] t-values,
//   acc[8][8] -> 2 W float4 loads per c serve 64 FMAs.
//   W is [c][v][o]: a wave reads a CONTIGUOUS 1024B chunk of one 256B-aligned
//   c-row per load instr -- no gather.
//   RULE: every index into acc[][] must be a compile-time constant (r3/r4
//   spills came from runtime-indexed acc -> scratch, +400-600MB WRITE_SIZE).
__global__ __launch_bounds__(256, 3) void k_gemm(const float* __restrict__ x,
                                                 const float* __restrict__ ws,
                                                 float* __restrict__ y,
                                                 float* __restrict__ gsum,
                                                 float* __restrict__ gsq) {
    __shared__ __align__(16) float Xs[CC*XSTR];
    __shared__ float s_sum[CC], s_sq[CC];
    int tid = threadIdx.x;
    int n = blockIdx.x >> 5, ch = blockIdx.x & 31;
    const float* xb = x + (size_t)n*(CC*TT*VV) + ch*LPOS;
    if (tid < CC) { s_sum[tid] = 0.f; s_sq[tid] = 0.f; }
    for (int i4 = tid; i4 < CC*(LPOS/4); i4 += 256) {
        int c = i4 / (LPOS/4), j4 = i4 - c*(LPOS/4);
        *(float4*)&Xs[c*XSTR + j4*4] = *(const float4*)(xb + c*(TT*VV) + j4*4);
    }
    __syncthreads();
    if (tid < 200) {
        int og = tid & 7, v = tid >> 3, o0 = og*8;
        float acc[TCH][8];
        #pragma unroll
        for (int t = 0; t < TCH; ++t)
            #pragma unroll
            for (int b = 0; b < 8; ++b) acc[t][b] = 0.f;
        const float* wp = ws + WS_W + v*CC + o0;   // [c][v][o], c-stride WROW
        const float* xp = Xs + v;
        #pragma unroll 4
        for (int c = 0; c < CC; ++c) {
            const float* wr = wp + c*WROW;
            float4 w0 = *(const float4*)(wr);
            float4 w1 = *(const float4*)(wr + 4);
            float xv[TCH];
            #pragma unroll
            for (int t = 0; t < TCH; ++t) xv[t] = xp[c*XSTR + t*VV];
            #pragma unroll
            for (int t = 0; t < TCH; ++t) {
                float xx = xv[t];
                acc[t][0] = fmaf(xx, w0.x, acc[t][0]);
                acc[t][1] = fmaf(xx, w0.y, acc[t][1]);
                acc[t][2] = fmaf(xx, w0.z, acc[t][2]);
                acc[t][3] = fmaf(xx, w0.w, acc[t][3]);
                acc[t][4] = fmaf(xx, w1.x, acc[t][4]);
                acc[t][5] = fmaf(xx, w1.y, acc[t][5]);
                acc[t][6] = fmaf(xx, w1.z, acc[t][6]);
                acc[t][7] = fmaf(xx, w1.w, acc[t][7]);
            }
        }
        // BN statistics on raw y (bias-free)
        #pragma unroll
        for (int oi = 0; oi < 8; ++oi) {
            float s1 = 0.f, s2 = 0.f;
            #pragma unroll
            for (int t = 0; t < TCH; ++t) {
                s1 += acc[t][oi];
                s2 = fmaf(acc[t][oi], acc[t][oi], s2);
            }
            atomicAdd(&s_sum[o0+oi], s1);
            atomicAdd(&s_sq[o0+oi],  s2);
        }
        // y writeback into the (dead) column-v address set of Xs.
        // Column v is touched only by tids 8v..8v+7 = one wave, which has
        // finished reading it (in-order wave) -> race-free, no barrier.
        // Static indices only; 8-way LDS bank conflict accepted (cheap).
        #pragma unroll
        for (int oi = 0; oi < 8; ++oi) {
            #pragma unroll
            for (int t = 0; t < TCH; ++t)
                Xs[(o0+oi)*XSTR + t*VV + v] = acc[t][oi];
        }
    }
    __syncthreads();
    // coalesced float4 y store: Xs rows hold y[o][t*25+v]
    float* ob = y + (size_t)n*(CC*TT*VV) + ch*LPOS;
    for (int i4 = tid; i4 < CC*(LPOS/4); i4 += 256) {
        int o = i4 / (LPOS/4), j4 = i4 - o*(LPOS/4);
        *(float4*)(ob + o*(TT*VV) + j4*4) = *(const float4*)&Xs[o*XSTR + j4*4];
    }
    if (tid < CC) {
        atomicAdd(&gsum[tid], s_sum[tid]);
        atomicAdd(&gsq[tid],  s_sq[tid]);
    }
}

// BN constants: alpha = gamma*rsqrt(var+eps); bfin = beta - alpha*meanY.
// (b_eff cancels: BN is invariant to per-channel constant shifts.)
__global__ void k_mid(float* __restrict__ ws, const float* __restrict__ gamma,
                      const float* __restrict__ beta) {
    int o = threadIdx.x;   // 64 threads, 1 block
    float meanY = ws[WS_GSUM + o] * (1.f/CNT);
    float ey2   = ws[WS_GSQ  + o] * (1.f/CNT);
    float var   = ey2 - meanY*meanY;               // biased variance
    float alpha = gamma[o] * rsqrtf(var + 1e-5f);
    ws[WS_ALPHA + o] = alpha;
    ws[WS_BFIN  + o] = fmaf(-alpha, meanY, beta[o]);
}

// pointwise finalize, in-place on d_out: out = relu(alpha[o]*y + bfin[o] + x)
// block = one (n,o) row of 6400 floats; alpha/bfin are wave-uniform scalars.
__global__ __launch_bounds__(256) void k_fin(const float* __restrict__ x,
                                             float* __restrict__ y,
                                             const float* __restrict__ ws) {
    int o = blockIdx.x & 63;
    float a = ws[WS_ALPHA + o];
    float b = ws[WS_BFIN  + o];
    size_t base = (size_t)blockIdx.x * (TT*VV);
    const float4* xp = (const float4*)(x + base);
    float4*       yp = (float4*)(y + base);
    for (int j = threadIdx.x; j < (TT*VV)/4; j += 256) {
        float4 yv = yp[j];
        float4 xv = xp[j];
        yv.x = fmaxf(fmaf(a, yv.x, b) + xv.x, 0.f);
        yv.y = fmaxf(fmaf(a, yv.y, b) + xv.y, 0.f);
        yv.z = fmaxf(fmaf(a, yv.z, b) + xv.z, 0.f);
        yv.w = fmaxf(fmaf(a, yv.w, b) + xv.w, 0.f);
        yp[j] = yv;
    }
}

extern "C" void kernel_launch(void* const* d_in, const int* in_sizes, int n_in,
                              void* d_out, int out_size, void* d_ws, size_t ws_size,
                              hipStream_t stream) {
    const float* x     = (const float*)d_in[0];
    const float* A     = (const float*)d_in[1];
    const float* ga    = (const float*)d_in[2];
    // d_in[3..6] = a_w, a_b, b_w, b_b: provably unused (softmax over contracted axis sums to 1)
    const float* gw    = (const float*)d_in[7];
    // d_in[8] = g_b: provably unused (per-channel bias cancels under training-mode BN)
    const float* gamma = (const float*)d_in[9];
    const float* beta  = (const float*)d_in[10];
    float* ws  = (float*)d_ws;
    float* out = (float*)d_out;

    hipLaunchKernelGGL(k_weff, dim3(400), dim3(256), 0, stream, A, ga, gw, ws);
    hipLaunchKernelGGL(k_gemm, dim3(NN*NCHUNK), dim3(256), 0, stream,
                       x, ws, out, ws + WS_GSUM, ws + WS_GSQ);
    hipLaunchKernelGGL(k_mid,  dim3(1), dim3(64), 0, stream, ws, gamma, beta);
    hipLaunchKernelGGL(k_fin,  dim3(NN*CC), dim3(256), 0, stream, x, out, ws);
}